// Round 7
// baseline (101.632 us; speedup 1.0000x reference)
//
#include <hip/hip_runtime.h>

#define BB 4
#define CCH 256
#define OCH 256
#define HH 64
#define WW 64
#define HWSZ 4096

typedef __bf16 bf16_t;
typedef bf16_t bf16x8 __attribute__((ext_vector_type(8)));
typedef float f32x4 __attribute__((ext_vector_type(4)));

__device__ __forceinline__ unsigned int bpack(float a, float b) {
    unsigned int ua = __float_as_uint(a);
    ua = (ua + 0x7FFFu + ((ua >> 16) & 1u)) >> 16;
    unsigned int ub = __float_as_uint(b);
    ub = (ub + 0x7FFFu + ((ub >> 16) & 1u)) >> 16;
    return ua | (ub << 16);
}
__device__ __forceinline__ float blo(unsigned int u) { return __uint_as_float(u << 16); }
__device__ __forceinline__ float bhi(unsigned int u) { return __uint_as_float(u & 0xFFFF0000u); }

// ---------------------------------------------------------------------------
// Kernel 0: transpose x [B][C][H][W] f32 -> xT [B][H][W][C] bf16
// ---------------------------------------------------------------------------
__global__ __launch_bounds__(256) void k_xT(const float* __restrict__ x,
                                            ushort* __restrict__ xT) {
    int b = blockIdx.x >> 6;
    int h = blockIdx.x & 63;
    int tid = threadIdx.x;
    int wv = tid >> 6;
    int lane = tid & 63;

    __shared__ unsigned int buf[64][130];

    const float* xp = x + ((size_t)b * CCH + wv * 64) * HWSZ + h * WW + lane;
#pragma unroll 8
    for (int i = 0; i < 32; ++i) {
        float a = xp[(size_t)(2 * i) * HWSZ];
        float c = xp[(size_t)(2 * i + 1) * HWSZ];
        buf[lane][wv * 32 + i] = bpack(a, c);
    }
    __syncthreads();

    ushort* dst = xT + ((size_t)(b * 64 + h) * 64) * 256;
#pragma unroll
    for (int r = 0; r < 16; ++r) {
        int idx = tid + r * 256;
        int w = idx >> 6;
        int q = idx & 63;
        uint2 v = *(const uint2*)&buf[w][2 * q];
        *(uint2*)(dst + (size_t)w * 256 + q * 4) = v;
    }
}

// ---------------------------------------------------------------------------
// Kernel prep (merged): w1F repack | w2F repack | P zero | out bias-prefill
// ---------------------------------------------------------------------------
__global__ void k_prep(const float* __restrict__ w_off, const float* __restrict__ w_def,
                       const float* __restrict__ b_def,
                       ushort* __restrict__ w1F, ushort* __restrict__ w2F,
                       float* __restrict__ P, float* __restrict__ out) {
    int i = blockIdx.x * blockDim.x + threadIdx.x;
    if (i < 73728) {
        int j = i & 7;
        int o = (i >> 3) & 31;
        int cSub = (i >> 8) & 31;
        int k = i >> 13;
        float v = 0.0f;
        if (o < 27) v = w_off[((size_t)o * CCH + cSub * 8 + j) * 9 + k];
        unsigned int u = __float_as_uint(v);
        u = (u + 0x7FFFu + ((u >> 16) & 1u)) >> 16;
        w1F[i] = (ushort)u;
        return;
    }
    i -= 73728;
    if (i < 589824) {
        int j = i & 7;
        int o = (i >> 3) & 255;
        int cg = (i >> 11) & 31;
        int k = i >> 16;
        float v = w_def[(size_t)o * 2304 + (cg * 8 + j) * 9 + k];
        unsigned int u = __float_as_uint(v);
        u = (u + 0x7FFFu + ((u >> 16) & 1u)) >> 16;
        w2F[i] = (ushort)u;
        return;
    }
    i -= 589824;
    if (i < 110592) {
        ((float4*)P)[i] = make_float4(0.f, 0.f, 0.f, 0.f);
        return;
    }
    i -= 110592;
    if (i < 1048576) {
        float v = b_def[(i >> 10) & 255];
        ((float4*)out)[i] = make_float4(v, v, v, v);
    }
}

// ---------------------------------------------------------------------------
// Kernel 2: pred conv via MFMA, B staged densely from xT. Atomic K-split x4.
// grid = 1024, XCD-swizzled.
// ---------------------------------------------------------------------------
__global__ __launch_bounds__(256) void k_pred3(const ushort* __restrict__ xT,
                                               const ushort* __restrict__ w1F,
                                               float* __restrict__ P) {
    int bid = blockIdx.x;
    int L = (bid & 7) * 128 + (bid >> 3);
    int g = L & 3;
    int h = (L >> 2) & 63;
    int b = L >> 8;
    int tid = threadIdx.x;
    int spx  = tid & 63;
    int sgrp = tid >> 6;
    int lane = tid & 63;
    int wv   = tid >> 6;
    int l16  = lane & 15;
    int lq   = lane >> 4;

    __shared__ ushort b_lds[2][4][4][16][8];

    const ushort* xTb = xT + (size_t)b * HWSZ * 256;
    const bf16x8* w1v = (const bf16x8*)w1F;

    f32x4 acc[2];
    acc[0] = (f32x4){0.f, 0.f, 0.f, 0.f};
    acc[1] = (f32x4){0.f, 0.f, 0.f, 0.f};

    auto stage = [&](int t, int buf) {
        int cg = 2 * g + (t >= 9);
        int k = t - (t >= 9 ? 9 : 0);
        int y   = h + k / 3 - 1;
        int pxs = spx + k % 3 - 1;
        bool ok = (y >= 0 && y < HH && pxs >= 0 && pxs < WW);
        uint4 v = make_uint4(0u, 0u, 0u, 0u);
        if (ok) v = *(const uint4*)(xTb + (size_t)(y * WW + pxs) * 256 + cg * 32 + sgrp * 8);
        *(uint4*)&b_lds[buf][sgrp][spx >> 4][spx & 15][0] = v;
    };

    stage(0, 0);
    __syncthreads();

    for (int t = 0; t < 18; ++t) {
        int cur = t & 1;
        int cg = 2 * g + (t >= 9);
        int k  = t - (t >= 9 ? 9 : 0);
        int row = k * 32 + cg * 4 + lq;
        bf16x8 a0 = w1v[(size_t)row * 32 + 0 * 16 + l16];
        bf16x8 a1 = w1v[(size_t)row * 32 + 1 * 16 + l16];
        if (t < 17) stage(t + 1, cur ^ 1);
        bf16x8 bfrag = *(const bf16x8*)&b_lds[cur][lq][wv][l16][0];
        acc[0] = __builtin_amdgcn_mfma_f32_16x16x32_bf16(a0, bfrag, acc[0], 0, 0, 0);
        acc[1] = __builtin_amdgcn_mfma_f32_16x16x32_bf16(a1, bfrag, acc[1], 0, 0, 0);
        __syncthreads();
    }

#pragma unroll
    for (int mf = 0; mf < 2; ++mf) {
#pragma unroll
        for (int r = 0; r < 4; ++r) {
            int o = mf * 16 + lq * 4 + r;
            if (o < 27) {
                atomicAdd(&P[((size_t)b * 27 + o) * HWSZ + h * WW + wv * 16 + l16],
                          acc[mf][r]);
            }
        }
    }
}

// ---------------------------------------------------------------------------
// Kernel 3: deformable sampling + bf16 MFMA GEMM. Tile 256o x 64px (full row),
// 512 thr = 8 waves (each 32o x 64px), cs-split x2 -> grid 512, XCD-swizzled.
// Chunk t (0..17): k = t>>1, c64 = t&1 -> channels cs*128 + c64*64 + [0,64).
// Staging: thread (px = tid>>3, cl = tid&7) gathers 8 ch (uint4) x 4 corners,
// combines, writes XOR-swizzled LDS. A-frags from L2 once per block.
// ---------------------------------------------------------------------------
__global__ __launch_bounds__(512) void k_deform6(const ushort* __restrict__ xT,
                                                 const float* __restrict__ P,
                                                 const float* __restrict__ b_off,
                                                 const ushort* __restrict__ w2F,
                                                 float* __restrict__ out) {
    int bid = blockIdx.x;
    int L = (bid & 7) * 64 + (bid >> 3);
    int cs = L & 1;
    int h  = (L >> 1) & 63;
    int b  = L >> 7;
    int tid = threadIdx.x;
    int lane = tid & 63;
    int wv   = tid >> 6;          // 0..7 -> o block = wv*32
    int l16  = lane & 15;
    int lq   = lane >> 4;
    int px   = tid >> 3;          // 0..63
    int cl   = tid & 7;           // 8-channel slot

    __shared__ ushort b_lds[2][8][4][16][8];   // [buf][kg][nt][p^kg][j] 16KB

    const char* xTc = (const char*)xT + (size_t)b * HWSZ * 512 + cs * 256 + cl * 16;
    const bf16x8* w2b = (const bf16x8*)w2F + (size_t)(cs * 16) * 256 + wv * 32 + l16;

    uint4* wdst[2];
    wdst[0] = (uint4*)&b_lds[0][cl][px >> 4][(px & 15) ^ cl][0];
    wdst[1] = (uint4*)&b_lds[1][cl][px >> 4][(px & 15) ^ cl][0];

    f32x4 acc[2][4];
#pragma unroll
    for (int mf = 0; mf < 2; ++mf)
#pragma unroll
        for (int nt = 0; nt < 4; ++nt) acc[mf][nt] = (f32x4){0.f, 0.f, 0.f, 0.f};

    float wgt[4];
    const char* aptr[4];
    const float* Pb = P + (size_t)b * 27 * HWSZ + h * WW + px;

    auto make_desc = [&](int k) {
        float offy = Pb[(size_t)(2 * k) * HWSZ] + b_off[2 * k];
        float offx = Pb[(size_t)(2 * k + 1) * HWSZ] + b_off[2 * k + 1];
        float mr   = Pb[(size_t)(18 + k) * HWSZ] + b_off[18 + k];
        float m = 1.0f / (1.0f + expf(-mr));
        float sy = offy + (float)(h + k / 3 - 1);
        float sx = offx + (float)(px + k % 3 - 1);
        float y0f = floorf(sy), x0f = floorf(sx);
        float ty = sy - y0f, tx = sx - x0f;
        int y0 = (int)y0f, x0 = (int)x0f;
#pragma unroll
        for (int dy = 0; dy < 2; ++dy) {
#pragma unroll
            for (int dx = 0; dx < 2; ++dx) {
                int yi = y0 + dy, xi = x0 + dx;
                bool ok = (yi >= 0 && yi < HH && xi >= 0 && xi < WW);
                float wg = (dy ? ty : 1.0f - ty) * (dx ? tx : 1.0f - tx) * m;
                wgt[dy * 2 + dx]  = ok ? wg : 0.0f;
                aptr[dy * 2 + dx] = xTc + (size_t)(ok ? (yi * WW + xi) : 0) * 512;
            }
        }
    };

    uint4 gb[4];
    auto combine = [&]() -> uint4 {
        uint4 r;
        {
            float lo = wgt[0]*blo(gb[0].x) + wgt[1]*blo(gb[1].x) + wgt[2]*blo(gb[2].x) + wgt[3]*blo(gb[3].x);
            float hi = wgt[0]*bhi(gb[0].x) + wgt[1]*bhi(gb[1].x) + wgt[2]*bhi(gb[2].x) + wgt[3]*bhi(gb[3].x);
            r.x = bpack(lo, hi);
        }
        {
            float lo = wgt[0]*blo(gb[0].y) + wgt[1]*blo(gb[1].y) + wgt[2]*blo(gb[2].y) + wgt[3]*blo(gb[3].y);
            float hi = wgt[0]*bhi(gb[0].y) + wgt[1]*bhi(gb[1].y) + wgt[2]*bhi(gb[2].y) + wgt[3]*bhi(gb[3].y);
            r.y = bpack(lo, hi);
        }
        {
            float lo = wgt[0]*blo(gb[0].z) + wgt[1]*blo(gb[1].z) + wgt[2]*blo(gb[2].z) + wgt[3]*blo(gb[3].z);
            float hi = wgt[0]*bhi(gb[0].z) + wgt[1]*bhi(gb[1].z) + wgt[2]*bhi(gb[2].z) + wgt[3]*bhi(gb[3].z);
            r.z = bpack(lo, hi);
        }
        {
            float lo = wgt[0]*blo(gb[0].w) + wgt[1]*blo(gb[1].w) + wgt[2]*blo(gb[2].w) + wgt[3]*blo(gb[3].w);
            float hi = wgt[0]*bhi(gb[0].w) + wgt[1]*bhi(gb[1].w) + wgt[2]*bhi(gb[2].w) + wgt[3]*bhi(gb[3].w);
            r.w = bpack(lo, hi);
        }
        return r;
    };

    bf16x8 aCur[2][2], aNxt[2][2];
    // A frag row for chunk t, k-group g: row = (t>>1)*32 + cs*16 + (t&1)*8 + g*4 + lq
    auto loadA = [&](int t, bf16x8 dst[2][2]) {
        size_t base = ((size_t)((t >> 1) * 32 + (t & 1) * 8) + lq) * 256;
#pragma unroll
        for (int g = 0; g < 2; ++g)
#pragma unroll
            for (int mf = 0; mf < 2; ++mf)
                dst[mf][g] = w2b[base + (size_t)g * 4 * 256 + mf * 16];
    };

    // prologue: chunk 0
    make_desc(0);
#pragma unroll
    for (int c = 0; c < 4; ++c) gb[c] = *(const uint4*)(aptr[c]);
    loadA(0, aCur);
    *wdst[0] = combine();
    __syncthreads();

#pragma unroll 2
    for (int t = 0; t < 18; ++t) {
        int cur = t & 1;
        bool pf = (t < 17);
        if (pf) {
            int tf = t + 1;
            if ((tf & 1) == 0) make_desc(tf >> 1);
            int off = (tf & 1) * 128;
#pragma unroll
            for (int c = 0; c < 4; ++c) gb[c] = *(const uint4*)(aptr[c] + off);
            loadA(tf, aNxt);
        }
        bf16x8 bfr[2][4];
#pragma unroll
        for (int g = 0; g < 2; ++g) {
            int kg = g * 4 + lq;
#pragma unroll
            for (int nt = 0; nt < 4; ++nt)
                bfr[g][nt] = *(const bf16x8*)&b_lds[cur][kg][nt][l16 ^ kg][0];
        }
#pragma unroll
        for (int g = 0; g < 2; ++g)
#pragma unroll
            for (int mf = 0; mf < 2; ++mf)
#pragma unroll
                for (int nt = 0; nt < 4; ++nt)
                    acc[mf][nt] = __builtin_amdgcn_mfma_f32_16x16x32_bf16(aCur[mf][g], bfr[g][nt], acc[mf][nt], 0, 0, 0);
        if (pf) {
            *wdst[cur ^ 1] = combine();
        }
        __syncthreads();
        if (pf) {
#pragma unroll
            for (int g = 0; g < 2; ++g)
#pragma unroll
                for (int mf = 0; mf < 2; ++mf) aCur[mf][g] = aNxt[mf][g];
        }
    }

    // epilogue: atomic accumulate (out prefilled with bias)
#pragma unroll
    for (int mf = 0; mf < 2; ++mf) {
#pragma unroll
        for (int nt = 0; nt < 4; ++nt) {
#pragma unroll
            for (int r = 0; r < 4; ++r) {
                int o = wv * 32 + mf * 16 + lq * 4 + r;
                atomicAdd(&out[((size_t)b * OCH + o) * HWSZ + h * WW + nt * 16 + l16],
                          acc[mf][nt][r]);
            }
        }
    }
}

// ---------------------------------------------------------------------------
extern "C" void kernel_launch(void* const* d_in, const int* in_sizes, int n_in,
                              void* d_out, int out_size, void* d_ws, size_t ws_size,
                              hipStream_t stream) {
    const float* x     = (const float*)d_in[0];
    const float* w_off = (const float*)d_in[1];
    const float* b_off = (const float*)d_in[2];
    const float* w_def = (const float*)d_in[3];
    const float* b_def = (const float*)d_in[4];
    float* out = (float*)d_out;

    float*  P   = (float*)d_ws;                            // 442368 f32
    ushort* w1F = (ushort*)(P + (size_t)BB * 27 * HWSZ);   // 73728 bf16
    ushort* w2F = w1F + 73728;                             // 589824 bf16
    ushort* xT  = w2F + 589824;                            // 4.19M bf16

    hipLaunchKernelGGL(k_prep, dim3(7120), dim3(256), 0, stream,
                       w_off, w_def, b_def, w1F, w2F, P, out);
    hipLaunchKernelGGL(k_xT, dim3(BB * HH), dim3(256), 0, stream, x, xT);
    hipLaunchKernelGGL(k_pred3, dim3(1024), dim3(256), 0, stream, xT, w1F, P);
    hipLaunchKernelGGL(k_deform6, dim3(512), dim3(512), 0, stream, xT, P, b_off, w2F, out);
}